// Round 5
// baseline (4607.853 us; speedup 1.0000x reference)
//
#include <hip/hip_runtime.h>

#define FPS_N   8192
#define FPS_T   1024
#define FPS_PPT 8   // points per thread = FPS_N / FPS_T

// asm-opaque single-rounded fp32 mul: cannot be contracted or reassociated.
__device__ __forceinline__ float mul_rn(float a, float b) {
    float r; asm("v_mul_f32 %0, %1, %2" : "=v"(r) : "v"(a), "v"(b)); return r;
}

// One block per batch. Coords in LDS (split x/y/z, broadcast reads); each
// thread's 8 points + running min-distances in registers.
// Distance uses the XLA-fused reduction arithmetic:
//   d = fma(dz,dz, fma(dy,dy, dx*dx))
// (XLA fuses (p-c)**2 into the axis=-1 reduce as an FMA chain; fma(dx,dx,0)
// equals an exact mul). __builtin_fmaf -> v_fma_f32, exact single-rounding.
// Argmax fused via u64 key: (dist_bits << 32) | ~index  -> max == argmax,
// ties -> smallest index (numpy/XLA first-occurrence).
__global__ __launch_bounds__(FPS_T) void fps_kernel(
    const float* __restrict__ coords,
    const int*   __restrict__ init_idx,
    int*         __restrict__ out_idx,
    int M)
{
    __shared__ float sx[FPS_N], sy[FPS_N], sz[FPS_N];
    __shared__ unsigned long long swave[FPS_T / 64];
    __shared__ int sFar;

    const int b   = blockIdx.x;
    const int tid = threadIdx.x;
    const float* cb = coords + (size_t)b * FPS_N * 3;

    // Load own 8 points: 24 contiguous floats = 6 float4 (coalesced)
    float f[24];
    const float4* cb4 = reinterpret_cast<const float4*>(cb);
    #pragma unroll
    for (int i = 0; i < 6; ++i) {
        float4 v = cb4[tid * 6 + i];
        f[i * 4 + 0] = v.x; f[i * 4 + 1] = v.y;
        f[i * 4 + 2] = v.z; f[i * 4 + 3] = v.w;
    }

    float px[FPS_PPT], py[FPS_PPT], pz[FPS_PPT], dist[FPS_PPT];
    const int base = tid * FPS_PPT;
    #pragma unroll
    for (int k = 0; k < FPS_PPT; ++k) {
        px[k] = f[3 * k + 0];
        py[k] = f[3 * k + 1];
        pz[k] = f[3 * k + 2];
        sx[base + k] = px[k];
        sy[base + k] = py[k];
        sz[base + k] = pz[k];
        dist[k] = 1e8f;   // BIG, matches reference (exactly representable)
    }
    __syncthreads();

    int far = init_idx[b];

    for (int s = 0; s < M; ++s) {
        if (tid == 0) out_idx[b * M + s] = far;   // record BEFORE update

        const float cx = sx[far], cy = sy[far], cz = sz[far];

        unsigned long long best = 0ull;
        #pragma unroll
        for (int k = 0; k < FPS_PPT; ++k) {
            float dx = px[k] - cx;      // single op, not a mul: uncontractable
            float dy = py[k] - cy;
            float dz = pz[k] - cz;
            // XLA-fused reduce chain: one rounding per step
            float d = __builtin_fmaf(dz, dz,
                        __builtin_fmaf(dy, dy, mul_rn(dx, dx)));
            float nd = fminf(dist[k], d);   // == minimum (no NaNs)
            dist[k] = nd;
            unsigned long long key =
                ((unsigned long long)__float_as_uint(nd) << 32) |
                (unsigned int)(~(base + k));
            best = key > best ? key : best;
        }

        // wave-64 butterfly max
        #pragma unroll
        for (int off = 32; off > 0; off >>= 1) {
            unsigned long long o = __shfl_xor(best, off, 64);
            best = o > best ? o : best;
        }
        if ((tid & 63) == 0) swave[tid >> 6] = best;
        __syncthreads();

        // wave 0 reduces the 16 per-wave winners
        if (tid < 64) {
            unsigned long long v = (tid < FPS_T / 64) ? swave[tid] : 0ull;
            #pragma unroll
            for (int off = 8; off > 0; off >>= 1) {
                unsigned long long o = __shfl_xor(v, off, 64);
                v = o > v ? o : v;
            }
            if (tid == 0) sFar = (int)(~(unsigned int)v);
        }
        __syncthreads();
        far = sFar;
    }
}

// One 64-thread block per output row: 64 x float4 = 256 floats of values,
// lanes 0-2 copy coords, lane 3 copies mask.
__global__ void gather_kernel(
    const float* __restrict__ coords,
    const float* __restrict__ values,
    const float* __restrict__ mask,
    const int*   __restrict__ idx,
    float* __restrict__ out_coords,
    float* __restrict__ out_values,
    float* __restrict__ out_mask,
    int N, int M, int D)
{
    const int bm = blockIdx.x;
    const int b  = bm / M;
    const int m  = bm - b * M;
    const int j  = idx[bm];
    const int l  = threadIdx.x;

    const float4* src = reinterpret_cast<const float4*>(values + ((size_t)b * N + j) * D);
    float4*       dst = reinterpret_cast<float4*>(out_values + ((size_t)b * M + m) * D);
    dst[l] = src[l];

    if (l < 3) {
        out_coords[((size_t)b * M + m) * 3 + l] = coords[((size_t)b * N + j) * 3 + l];
    } else if (l == 3) {
        out_mask[(size_t)b * M + m] = mask[(size_t)b * N + j];
    }
}

extern "C" void kernel_launch(void* const* d_in, const int* in_sizes, int n_in,
                              void* d_out, int out_size, void* d_ws, size_t ws_size,
                              hipStream_t stream)
{
    const float* coords   = (const float*)d_in[0];
    const float* values   = (const float*)d_in[1];
    const float* mask     = (const float*)d_in[2];
    const int*   init_idx = (const int*)d_in[3];

    const int B = in_sizes[3];
    const int N = in_sizes[2] / B;            // 8192
    const int D = in_sizes[1] / (B * N);      // 256
    const int M = N / 2;                      // SAMPLING_FRACTION = 0.5 -> 4096

    float* out_coords = (float*)d_out;
    float* out_values = out_coords + (size_t)B * M * 3;
    float* out_mask   = out_values + (size_t)B * M * D;

    int* idx = (int*)d_ws;   // B*M ints = 256 KB scratch

    fps_kernel<<<B, FPS_T, 0, stream>>>(coords, init_idx, idx, M);
    gather_kernel<<<B * M, D / 4, 0, stream>>>(coords, values, mask, idx,
                                               out_coords, out_values, out_mask,
                                               N, M, D);
}

// Round 7
// 3857.206 us; speedup vs baseline: 1.1946x; 1.1946x over previous
//
#include <hip/hip_runtime.h>

#define FPS_N   8192
#define FPS_T   1024
#define FPS_W   (FPS_T / 64)    // 16 waves
#define FPS_PPT (FPS_N / FPS_T) // 8 points per thread

// asm-opaque single-rounded fp32 mul: cannot be contracted or reassociated.
__device__ __forceinline__ float mul_rn(float a, float b) {
    float r; asm("v_mul_f32 %0, %1, %2" : "=v"(r) : "v"(a), "v"(b)); return r;
}

// One DPP max step: x = max(x, lane-shifted x). DPP ctrl must be an ICE ->
// template parameter. bound_ctrl=true: OOB sources read 0.0f, harmless
// because every value here is >= 0.
template<int CTRL>
__device__ __forceinline__ float dpp_max_step(float x) {
    int s = __builtin_amdgcn_update_dpp(0, __float_as_int(x), CTRL, 0xf, 0xf, true);
    return fmaxf(x, __int_as_float(s));
}

// Canonical wave64 max reduce on the VALU pipe (no LDS traffic):
// row_shr 1/2/4/8 -> per-row suffix max; row_bcast15/31 stitch rows;
// lane 63 holds the wave max; readlane broadcasts it as a uniform.
// Requires x >= 0 (true: squared distances, BIG=1e8).
__device__ __forceinline__ float wave_max_nn(float x) {
    x = dpp_max_step<0x111>(x);  // row_shr:1
    x = dpp_max_step<0x112>(x);  // row_shr:2
    x = dpp_max_step<0x114>(x);  // row_shr:4
    x = dpp_max_step<0x118>(x);  // row_shr:8
    x = dpp_max_step<0x142>(x);  // row_bcast:15
    x = dpp_max_step<0x143>(x);  // row_bcast:31
    return __int_as_float(__builtin_amdgcn_readlane(__float_as_int(x), 63));
}

// One block per batch. Coords in LDS (split x/y/z, broadcast reads); each
// thread's 8 points + running min-distances in registers.
// Distance is the XLA-fused chain (frozen, bit-exact vs reference):
//   d = fma(dz,dz, fma(dy,dy, dx*dx))
// Selection: argmax with first-occurrence ties. Point ownership is
// contiguous (thread tid owns tid*8 .. tid*8+7), so smallest-lane /
// smallest-wave == smallest global index; ballot+ctz preserves numpy
// tie-break exactly.
__global__ __launch_bounds__(FPS_T) void fps_kernel(
    const float* __restrict__ coords,
    const int*   __restrict__ init_idx,
    int*         __restrict__ out_idx,
    int M)
{
    __shared__ float sx[FPS_N], sy[FPS_N], sz[FPS_N];
    __shared__ float swd[2][FPS_W];   // parity-double-buffered wave winners
    __shared__ int   swi[2][FPS_W];

    const int b    = blockIdx.x;
    const int tid  = threadIdx.x;
    const int lane = tid & 63;
    const float* cb = coords + (size_t)b * FPS_N * 3;

    // Load own 8 points: 24 contiguous floats = 6 float4 (coalesced)
    float f[24];
    const float4* cb4 = reinterpret_cast<const float4*>(cb);
    #pragma unroll
    for (int i = 0; i < 6; ++i) {
        float4 v = cb4[tid * 6 + i];
        f[i * 4 + 0] = v.x; f[i * 4 + 1] = v.y;
        f[i * 4 + 2] = v.z; f[i * 4 + 3] = v.w;
    }

    float px[FPS_PPT], py[FPS_PPT], pz[FPS_PPT], dist[FPS_PPT];
    const int base = tid * FPS_PPT;
    #pragma unroll
    for (int k = 0; k < FPS_PPT; ++k) {
        px[k] = f[3 * k + 0];
        py[k] = f[3 * k + 1];
        pz[k] = f[3 * k + 2];
        sx[base + k] = px[k];
        sy[base + k] = py[k];
        sz[base + k] = pz[k];
        dist[k] = 1e8f;   // BIG, matches reference
    }
    __syncthreads();

    int far = init_idx[b];

    for (int s = 0; s < M; ++s) {
        if (tid == 0) out_idx[b * M + s] = far;   // record BEFORE update

        const float cx = sx[far], cy = sy[far], cz = sz[far];  // LDS broadcast

        // --- distance update + running thread max (math frozen) ---
        float m = 0.0f;   // all dists >= 0
        #pragma unroll
        for (int k = 0; k < FPS_PPT; ++k) {
            float dx = px[k] - cx;
            float dy = py[k] - cy;
            float dz = pz[k] - cz;
            float d  = __builtin_fmaf(dz, dz,
                         __builtin_fmaf(dy, dy, mul_rn(dx, dx)));
            float nd = fminf(dist[k], d);
            dist[k]  = nd;
            m = fmaxf(m, nd);
        }
        // first k achieving the max (descending scan -> smallest k wins)
        int myidx = base;
        #pragma unroll
        for (int k = FPS_PPT - 1; k >= 0; --k)
            myidx = (dist[k] == m) ? base + k : myidx;

        // --- wave reduce on VALU pipe ---
        float wm = wave_max_nn(m);
        unsigned long long ball = __ballot(m == wm);
        int fl   = (int)__builtin_ctzll(ball);          // smallest lane = smallest idx
        int widx = __builtin_amdgcn_readlane(myidx, fl);

        const int par = s & 1;
        if (lane == 0) {
            swd[par][tid >> 6] = wm;
            swi[par][tid >> 6] = widx;
        }
        __syncthreads();   // the ONLY barrier per iteration

        // --- every wave redundantly reduces the 16 winners ---
        float wv  = swd[par][lane & (FPS_W - 1)];
        int   wxi = swi[par][lane & (FPS_W - 1)];
        float gm  = wave_max_nn(wv);
        unsigned long long b2 = __ballot(wv == gm);
        int f2 = (int)__builtin_ctzll(b2);              // smallest wave = smallest idx
        far = __builtin_amdgcn_readlane(wxi, f2);
    }
}

// One 64-thread block per output row: 64 x float4 = 256 floats of values,
// lanes 0-2 copy coords, lane 3 copies mask.
__global__ void gather_kernel(
    const float* __restrict__ coords,
    const float* __restrict__ values,
    const float* __restrict__ mask,
    const int*   __restrict__ idx,
    float* __restrict__ out_coords,
    float* __restrict__ out_values,
    float* __restrict__ out_mask,
    int N, int M, int D)
{
    const int bm = blockIdx.x;
    const int b  = bm / M;
    const int m  = bm - b * M;
    const int j  = idx[bm];
    const int l  = threadIdx.x;

    const float4* src = reinterpret_cast<const float4*>(values + ((size_t)b * N + j) * D);
    float4*       dst = reinterpret_cast<float4*>(out_values + ((size_t)b * M + m) * D);
    dst[l] = src[l];

    if (l < 3) {
        out_coords[((size_t)b * M + m) * 3 + l] = coords[((size_t)b * N + j) * 3 + l];
    } else if (l == 3) {
        out_mask[(size_t)b * M + m] = mask[(size_t)b * N + j];
    }
}

extern "C" void kernel_launch(void* const* d_in, const int* in_sizes, int n_in,
                              void* d_out, int out_size, void* d_ws, size_t ws_size,
                              hipStream_t stream)
{
    const float* coords   = (const float*)d_in[0];
    const float* values   = (const float*)d_in[1];
    const float* mask     = (const float*)d_in[2];
    const int*   init_idx = (const int*)d_in[3];

    const int B = in_sizes[3];
    const int N = in_sizes[2] / B;            // 8192
    const int D = in_sizes[1] / (B * N);      // 256
    const int M = N / 2;                      // SAMPLING_FRACTION = 0.5 -> 4096

    float* out_coords = (float*)d_out;
    float* out_values = out_coords + (size_t)B * M * 3;
    float* out_mask   = out_values + (size_t)B * M * D;

    int* idx = (int*)d_ws;   // B*M ints = 256 KB scratch

    fps_kernel<<<B, FPS_T, 0, stream>>>(coords, init_idx, idx, M);
    gather_kernel<<<B * M, D / 4, 0, stream>>>(coords, values, mask, idx,
                                               out_coords, out_values, out_mask,
                                               N, M, D);
}

// Round 8
// 3791.868 us; speedup vs baseline: 1.2152x; 1.0172x over previous
//
#include <hip/hip_runtime.h>

#define FPS_N   8192
#define FPS_T   512
#define FPS_W   (FPS_T / 64)    // 8 waves
#define FPS_PPT (FPS_N / FPS_T) // 16 points per thread
#define FPS_PR  (FPS_PPT / 2)   // 8 point-pairs per thread

typedef float v2f __attribute__((ext_vector_type(2)));

// Packed fp32 ops (VOP3P): two independent IEEE-RN f32 ops per instruction.
// asm-opaque -> no contraction/reassociation. Halves issue count of the
// frozen distance chain. Subtraction is done as a + (-c): bit-exact.
__device__ __forceinline__ v2f pk_add(v2f a, v2f b) {
    v2f r; asm("v_pk_add_f32 %0, %1, %2" : "=v"(r) : "v"(a), "v"(b)); return r;
}
__device__ __forceinline__ v2f pk_mul(v2f a, v2f b) {
    v2f r; asm("v_pk_mul_f32 %0, %1, %2" : "=v"(r) : "v"(a), "v"(b)); return r;
}
__device__ __forceinline__ v2f pk_fma(v2f a, v2f b, v2f c) {
    v2f r; asm("v_pk_fma_f32 %0, %1, %2, %3" : "=v"(r) : "v"(a), "v"(b), "v"(c)); return r;
}

// One DPP max step: x = max(x, lane-shifted x). bound_ctrl=true -> OOB
// sources read 0.0f, harmless because every value here is >= 0.
template<int CTRL>
__device__ __forceinline__ float dpp_max_step(float x) {
    int s = __builtin_amdgcn_update_dpp(0, __float_as_int(x), CTRL, 0xf, 0xf, true);
    return fmaxf(x, __int_as_float(s));
}

// Full wave64 max on the VALU pipe; result broadcast from lane 63.
__device__ __forceinline__ float wave_max_nn(float x) {
    x = dpp_max_step<0x111>(x);  // row_shr:1
    x = dpp_max_step<0x112>(x);  // row_shr:2
    x = dpp_max_step<0x114>(x);  // row_shr:4
    x = dpp_max_step<0x118>(x);  // row_shr:8
    x = dpp_max_step<0x142>(x);  // row_bcast:15
    x = dpp_max_step<0x143>(x);  // row_bcast:31
    return __int_as_float(__builtin_amdgcn_readlane(__float_as_int(x), 63));
}

__device__ __forceinline__ float readlane_f(float x, int l) {
    return __int_as_float(__builtin_amdgcn_readlane(__float_as_int(x), l));
}

// One block per batch, 512 threads x 16 points. Coords in LDS (split x/y/z)
// only for candidate-coord prefetch; points + min-distances live packed in
// registers. Distance is the frozen XLA chain, per packed half:
//   d = fma(dz,dz, fma(dy,dy, dx*dx))
// Selection: argmax, first-occurrence ties. Ownership contiguous ascending
// (thread t owns t*16..t*16+15) => smallest lane / smallest wave == smallest
// global index; ballot+ctz preserves the numpy tie-break exactly.
__global__ __launch_bounds__(FPS_T) void fps_kernel(
    const float* __restrict__ coords,
    const int*   __restrict__ init_idx,
    int*         __restrict__ out_idx,
    int M)
{
    __shared__ float sx[FPS_N], sy[FPS_N], sz[FPS_N];
    __shared__ float swd[2][FPS_W];   // parity-double-buffered wave winners
    __shared__ int   swi[2][FPS_W];
    __shared__ float scx[2][FPS_W], scy[2][FPS_W], scz[2][FPS_W];

    const int b    = blockIdx.x;
    const int tid  = threadIdx.x;
    const int lane = tid & 63;
    const int wv   = tid >> 6;
    const float* cb = coords + (size_t)b * FPS_N * 3;

    // Load own 16 points: 48 contiguous floats = 12 float4 (coalesced)
    float f[48];
    const float4* cb4 = reinterpret_cast<const float4*>(cb);
    #pragma unroll
    for (int i = 0; i < 12; ++i) {
        float4 v = cb4[tid * 12 + i];
        f[i * 4 + 0] = v.x; f[i * 4 + 1] = v.y;
        f[i * 4 + 2] = v.z; f[i * 4 + 3] = v.w;
    }

    v2f px[FPS_PR], py[FPS_PR], pz[FPS_PR], dist[FPS_PR];
    const int base = tid * FPS_PPT;
    #pragma unroll
    for (int k = 0; k < FPS_PPT; ++k) {
        sx[base + k] = f[3 * k + 0];
        sy[base + k] = f[3 * k + 1];
        sz[base + k] = f[3 * k + 2];
    }
    #pragma unroll
    for (int j = 0; j < FPS_PR; ++j) {
        px[j] = v2f{f[6 * j + 0], f[6 * j + 3]};
        py[j] = v2f{f[6 * j + 1], f[6 * j + 4]};
        pz[j] = v2f{f[6 * j + 2], f[6 * j + 5]};
        dist[j] = v2f{1e8f, 1e8f};   // BIG, matches reference
    }
    __syncthreads();

    int far = init_idx[b];
    float cx = sx[far], cy = sy[far], cz = sz[far];   // LDS broadcast (once)

    for (int s = 0; s < M; ++s) {
        if (tid == 0) out_idx[b * M + s] = far;   // record BEFORE update

        // --- distance update + running thread max (math frozen) ---
        const v2f ncx = v2f{-cx, -cx};   // a + (-c) == a - c, bit-exact
        const v2f ncy = v2f{-cy, -cy};
        const v2f ncz = v2f{-cz, -cz};
        float m = 0.0f;   // all dists >= 0
        #pragma unroll
        for (int j = 0; j < FPS_PR; ++j) {
            v2f dx2 = pk_add(px[j], ncx);
            v2f dy2 = pk_add(py[j], ncy);
            v2f dz2 = pk_add(pz[j], ncz);
            v2f d2  = pk_fma(dz2, dz2, pk_fma(dy2, dy2, pk_mul(dx2, dx2)));
            v2f nd;
            nd.x = fminf(dist[j].x, d2.x);
            nd.y = fminf(dist[j].y, d2.y);
            dist[j] = nd;
            m = fmaxf(m, fmaxf(nd.x, nd.y));   // -> v_max3 fusion
        }
        // first k achieving the max (descending scan -> smallest k wins)
        int myidx = base;
        #pragma unroll
        for (int j = FPS_PR - 1; j >= 0; --j) {
            myidx = (dist[j].y == m) ? base + 2 * j + 1 : myidx;
            myidx = (dist[j].x == m) ? base + 2 * j     : myidx;
        }

        // --- stage 1: wave reduce on VALU pipe + candidate-coord prefetch ---
        float wm = wave_max_nn(m);
        unsigned long long ball = __ballot(m == wm);
        int fl   = (int)__builtin_ctzll(ball);          // smallest lane = smallest idx
        int widx = __builtin_amdgcn_readlane(myidx, fl);

        const int par = s & 1;
        if (lane == 0) {
            float wcx = sx[widx], wcy = sy[widx], wcz = sz[widx]; // prefetch
            swd[par][wv] = wm;  swi[par][wv] = widx;
            scx[par][wv] = wcx; scy[par][wv] = wcy; scz[par][wv] = wcz;
        }
        __syncthreads();   // the ONLY barrier per iteration

        // --- stage 2: every wave reduces the 8 winners; coords by readlane ---
        float dval = 0.0f, cxl = 0.0f, cyl = 0.0f, czl = 0.0f;
        int   idxl = 0;
        if (lane < FPS_W) {
            dval = swd[par][lane]; idxl = swi[par][lane];
            cxl  = scx[par][lane]; cyl = scy[par][lane]; czl = scz[par][lane];
        }
        float g = dval;
        g = dpp_max_step<0x111>(g);   // row_shr:1
        g = dpp_max_step<0x112>(g);   // row_shr:2
        g = dpp_max_step<0x114>(g);   // row_shr:4  -> lane 7 = max(l0..l7)
        float gm = readlane_f(g, 7);
        unsigned long long b2 = __ballot(lane < FPS_W && dval == gm);
        int w2 = (int)__builtin_ctzll(b2);              // smallest wave = smallest idx
        far = __builtin_amdgcn_readlane(idxl, w2);
        cx  = readlane_f(cxl, w2);
        cy  = readlane_f(cyl, w2);
        cz  = readlane_f(czl, w2);
    }
}

// One 64-thread block per output row: 64 x float4 = 256 floats of values,
// lanes 0-2 copy coords, lane 3 copies mask.
__global__ void gather_kernel(
    const float* __restrict__ coords,
    const float* __restrict__ values,
    const float* __restrict__ mask,
    const int*   __restrict__ idx,
    float* __restrict__ out_coords,
    float* __restrict__ out_values,
    float* __restrict__ out_mask,
    int N, int M, int D)
{
    const int bm = blockIdx.x;
    const int b  = bm / M;
    const int m  = bm - b * M;
    const int j  = idx[bm];
    const int l  = threadIdx.x;

    const float4* src = reinterpret_cast<const float4*>(values + ((size_t)b * N + j) * D);
    float4*       dst = reinterpret_cast<float4*>(out_values + ((size_t)b * M + m) * D);
    dst[l] = src[l];

    if (l < 3) {
        out_coords[((size_t)b * M + m) * 3 + l] = coords[((size_t)b * N + j) * 3 + l];
    } else if (l == 3) {
        out_mask[(size_t)b * M + m] = mask[(size_t)b * N + j];
    }
}

extern "C" void kernel_launch(void* const* d_in, const int* in_sizes, int n_in,
                              void* d_out, int out_size, void* d_ws, size_t ws_size,
                              hipStream_t stream)
{
    const float* coords   = (const float*)d_in[0];
    const float* values   = (const float*)d_in[1];
    const float* mask     = (const float*)d_in[2];
    const int*   init_idx = (const int*)d_in[3];

    const int B = in_sizes[3];
    const int N = in_sizes[2] / B;            // 8192
    const int D = in_sizes[1] / (B * N);      // 256
    const int M = N / 2;                      // SAMPLING_FRACTION = 0.5 -> 4096

    float* out_coords = (float*)d_out;
    float* out_values = out_coords + (size_t)B * M * 3;
    float* out_mask   = out_values + (size_t)B * M * D;

    int* idx = (int*)d_ws;   // B*M ints = 256 KB scratch

    fps_kernel<<<B, FPS_T, 0, stream>>>(coords, init_idx, idx, M);
    gather_kernel<<<B * M, D / 4, 0, stream>>>(coords, values, mask, idx,
                                               out_coords, out_values, out_mask,
                                               N, M, D);
}